// Round 6
// baseline (438.526 us; speedup 1.0000x reference)
//
#include <hip/hip_runtime.h>

#define PBLK 256

typedef __attribute__((ext_vector_type(8))) short bf16x8;
typedef __attribute__((ext_vector_type(16))) float f32x16;

struct IPerm { int v[12]; };   // up to 3 perms x 4 atoms (inverse perms)

__device__ __forceinline__ unsigned short f2bf(float x) {
    unsigned int u = __builtin_bit_cast(unsigned int, x);
    u += 0x7fffu + ((u >> 16) & 1u);
    return (unsigned short)(u >> 16);
}

// ---- pre-pass 1: node_reps fp32 -> bf16 ----
__global__ void conv_node(const float* __restrict__ x, unsigned short* __restrict__ o, int n4) {
    int tid = blockIdx.x * PBLK + threadIdx.x;
    if (tid >= n4) return;
    const float4 v = reinterpret_cast<const float4*>(x)[tid];
    ushort4 r;
    r.x = f2bf(v.x); r.y = f2bf(v.y); r.z = f2bf(v.z); r.w = f2bf(v.w);
    reinterpret_cast<ushort4*>(o)[tid] = r;
}

// ---- pre-pass 2: pack w1 into per-perm 32x32x16 B-fragment layout ----
// o[(((p*4+ct)*KS + s)*64 + l)*8 + j]; lane l -> col = ct*32+(l&31),
// k = s*16 + (l>>5)*8 + j; source row permuted per inverse perm on 128-blocks.
// (This layout was HW-verified correct in round 5.)
template<int K>
__global__ void pack_w1(const float* __restrict__ w1, unsigned short* __restrict__ o,
                        int nperms, IPerm ip) {
    constexpr int KS = K / 16;
    const int per = K * 128;
    int tid = blockIdx.x * PBLK + threadIdx.x;
    if (tid >= nperms * per) return;
    const int p = tid / per;
    const int e = tid - p * per;
    const int j = e & 7;
    const int l = (e >> 3) & 63;
    const int cts = e >> 9;            // ct*KS + s
    const int s  = cts % KS;
    const int ct = cts / KS;
    const int col = ct * 32 + (l & 31);
    const int k = s * 16 + (l >> 5) * 8 + j;
    const int srow = ip.v[p * 4 + (k >> 7)] * 128 + (k & 127);
    o[tid] = f2bf(w1[(size_t)srow * 128 + col]);
}

// ---- main term kernel: barrier-free, register-direct ----
// 256 threads = 4 waves (2 row-grp x 2 col-grp); wave tile 32 rows x 64 cols,
// mfma_f32_32x32x16_bf16. A-fragments gathered straight from global into
// registers (double-buffered one atom ahead); B-fragments in 8-load register
// groups (double-buffered one group ahead). No LDS/barriers in the main loop;
// one __syncthreads before the layer-2 reduction.
template<int NATOMS, int NPERMS, int DOUT>
__global__ __launch_bounds__(256, 2) void term_mfma(
    const unsigned short* __restrict__ nodeb,  // (N,128) bf16
    const int* __restrict__ idx,               // (nrows,NATOMS) or nullptr
    const unsigned short* __restrict__ pack,   // NPERMS*K*128 bf16 packed
    const float* __restrict__ b1,              // (128)
    const float* __restrict__ w2,              // (128,DOUT)
    const float* __restrict__ b2,              // (DOUT)
    float* __restrict__ out,                   // (nrows,DOUT)
    int nrows)
{
    constexpr int KS = NATOMS * 8;             // k-steps of 16 (total)
    constexpr int NG = NPERMS * 2;             // B groups per atom (8 frags each)
    __shared__ float hs[64 * 128];             // 32KB h staging

    const int t   = threadIdx.x;
    const int l   = t & 63;
    const int w   = t >> 6;
    const int rg  = w >> 1;                    // row group (0..1)
    const int cg  = w & 1;                     // col group (0..1)
    const int l31 = l & 31;
    const int hi  = l >> 5;
    const int r0  = blockIdx.x * 64;

    // per-lane gather indices (lane's own output row)
    int rowi = r0 + rg * 32 + l31;
    if (rowi >= nrows) rowi = nrows - 1;
    int nrow[NATOMS];
    #pragma unroll
    for (int a = 0; a < NATOMS; ++a)
        nrow[a] = idx ? idx[rowi * NATOMS + a] : rowi;

    const int colb = cg * 64 + l31;
    f32x16 acc[NPERMS][2];
    {
        const float b0 = b1[colb], b32 = b1[colb + 32];
        #pragma unroll
        for (int p = 0; p < NPERMS; ++p)
            #pragma unroll
            for (int i = 0; i < 16; ++i) { acc[p][0][i] = b0; acc[p][1][i] = b32; }
    }

    bf16x8 A[2][8];
#define LOADA(buf_, a_) { _Pragma("unroll")                                        \
    for (int s_ = 0; s_ < 8; ++s_)                                                 \
        A[buf_][s_] = *reinterpret_cast<const bf16x8*>(                            \
            nodeb + (size_t)nrow[a_] * 128 + s_ * 16 + hi * 8); }

#define LOADB(dst_, a_, g_) { const int p_ = (g_) >> 1, sh_ = (g_) & 1;            \
    _Pragma("unroll")                                                              \
    for (int s4_ = 0; s4_ < 4; ++s4_) { _Pragma("unroll")                          \
    for (int ct_ = 0; ct_ < 2; ++ct_)                                              \
        dst_[s4_ * 2 + ct_] = *reinterpret_cast<const bf16x8*>(                    \
            pack + (((size_t)(p_ * 4 + cg * 2 + ct_) * KS + (a_) * 8 + sh_ * 4 + s4_) * 64 + l) * 8); } }

    LOADA(0, 0);
    #pragma unroll
    for (int a = 0; a < NATOMS; ++a) {
        if (a + 1 < NATOMS) LOADA((a + 1) & 1, a + 1);   // next atom in flight
        bf16x8 Bb[2][8];
        LOADB(Bb[0], a, 0);
        #pragma unroll
        for (int g = 0; g < NG; ++g) {
            if (g + 1 < NG) LOADB(Bb[(g + 1) & 1], a, g + 1);   // next group in flight
            const int p = g >> 1, sh = g & 1;
            #pragma unroll
            for (int s4 = 0; s4 < 4; ++s4)
                #pragma unroll
                for (int ct = 0; ct < 2; ++ct)
                    acc[p][ct] = __builtin_amdgcn_mfma_f32_32x32x16_bf16(
                        A[a & 1][sh * 4 + s4], Bb[g & 1][s4 * 2 + ct], acc[p][ct], 0, 0, 0);
        }
    }
#undef LOADA
#undef LOADB

    // ---- h = sum_p relu(acc_p) -> LDS (fp32, swizzled); C layout per m74/m101 ----
    #pragma unroll
    for (int i = 0; i < 16; ++i) {
        const int rowl = rg * 32 + (i & 3) + 8 * (i >> 2) + 4 * hi;
        #pragma unroll
        for (int ct = 0; ct < 2; ++ct) {
            float v = 0.0f;
            #pragma unroll
            for (int p = 0; p < NPERMS; ++p) v += fmaxf(acc[p][ct][i], 0.0f);
            hs[rowl * 128 + ((colb + ct * 32) ^ ((rowl & 7) << 2))] = v;
        }
    }
    __syncthreads();

    // ---- layer 2: y = h @ w2 + NPERMS*b2 ----
    for (int q = t; q < 64 * DOUT; q += 256) {
        const int r = q / DOUT;
        const int o = q - r * DOUT;
        float y0 = 0.f, y1 = 0.f, y2 = 0.f, y3 = 0.f;
        #pragma unroll 4
        for (int c = 0; c < 128; c += 4) {
            y0 += hs[r * 128 + ((c    ) ^ ((r & 7) << 2))] * w2[(size_t)(c    ) * DOUT + o];
            y1 += hs[r * 128 + ((c + 1) ^ ((r & 7) << 2))] * w2[(size_t)(c + 1) * DOUT + o];
            y2 += hs[r * 128 + ((c + 2) ^ ((r & 7) << 2))] * w2[(size_t)(c + 2) * DOUT + o];
            y3 += hs[r * 128 + ((c + 3) ^ ((r & 7) << 2))] * w2[(size_t)(c + 3) * DOUT + o];
        }
        const float y = b2[o] * (float)NPERMS + ((y0 + y1) + (y2 + y3));
        const int row = r0 + r;
        if (row < nrows) out[(size_t)row * DOUT + o] = y;
    }
}

extern "C" void kernel_launch(void* const* d_in, const int* in_sizes, int n_in,
                              void* d_out, int out_size, void* d_ws, size_t ws_size,
                              hipStream_t stream) {
    const float* node = (const float*)d_in[0];
    const int* bidx = (const int*)d_in[1];
    const int* gidx = (const int*)d_in[2];
    const int* pidx = (const int*)d_in[3];
    const int* iidx = (const int*)d_in[4];

    const float* aw1 = (const float*)d_in[5];
    const float* ab1 = (const float*)d_in[6];
    const float* aw2 = (const float*)d_in[7];
    const float* ab2 = (const float*)d_in[8];
    const float* bw1 = (const float*)d_in[9];
    const float* bb1 = (const float*)d_in[10];
    const float* bw2 = (const float*)d_in[11];
    const float* bb2 = (const float*)d_in[12];
    const float* gw1 = (const float*)d_in[13];
    const float* gb1 = (const float*)d_in[14];
    const float* gw2 = (const float*)d_in[15];
    const float* gb2 = (const float*)d_in[16];
    const float* pw1 = (const float*)d_in[17];
    const float* pb1 = (const float*)d_in[18];
    const float* pw2 = (const float*)d_in[19];
    const float* pb2 = (const float*)d_in[20];
    const float* iw1 = (const float*)d_in[21];
    const float* ib1 = (const float*)d_in[22];
    const float* iw2 = (const float*)d_in[23];
    const float* ib2 = (const float*)d_in[24];

    const int N  = in_sizes[0] / 128;
    const int NB = in_sizes[1] / 2;
    const int NA = in_sizes[2] / 3;
    const int NP = in_sizes[3] / 4;
    const int NI = in_sizes[4] / 4;

    float* out   = (float*)d_out;
    float* out_a = out;
    float* out_b = out_a + (size_t)N  * 2;
    float* out_g = out_b + (size_t)NB * 2;
    float* out_p = out_g + (size_t)NA * 2;
    float* out_i = out_p + (size_t)NP * 6;

    // ---- workspace layout (bf16 elements) ----
    unsigned short* nodeb = (unsigned short*)d_ws;
    size_t off = (size_t)N * 128;
    unsigned short* packA = nodeb + off; off += (size_t)1 * 128 * 128;
    unsigned short* packB = nodeb + off; off += (size_t)2 * 256 * 128;
    unsigned short* packG = nodeb + off; off += (size_t)2 * 384 * 128;
    unsigned short* packP = nodeb + off; off += (size_t)2 * 512 * 128;
    unsigned short* packI = nodeb + off; off += (size_t)3 * 512 * 128;

    // ---- pre-pass: convert node, pack weights ----
    {
        const int n4 = N * 128 / 4;
        conv_node<<<(n4 + PBLK - 1) / PBLK, PBLK, 0, stream>>>(node, nodeb, n4);
    }
    IPerm ipa{{0,0,0,0,  0,0,0,0,  0,0,0,0}};
    IPerm ipb{{0,1,0,0,  1,0,0,0,  0,0,0,0}};
    IPerm ipg{{0,1,2,0,  2,1,0,0,  0,0,0,0}};
    IPerm ipp{{0,1,2,3,  3,2,1,0,  0,0,0,0}};
    IPerm ipi{{0,1,2,3,  3,1,0,2,  2,1,3,0}};   // inverses of (0123),(2130),(3102)

    pack_w1<128><<<(1 * 128 * 128 + PBLK - 1) / PBLK, PBLK, 0, stream>>>(aw1, packA, 1, ipa);
    pack_w1<256><<<(2 * 256 * 128 + PBLK - 1) / PBLK, PBLK, 0, stream>>>(bw1, packB, 2, ipb);
    pack_w1<384><<<(2 * 384 * 128 + PBLK - 1) / PBLK, PBLK, 0, stream>>>(gw1, packG, 2, ipg);
    pack_w1<512><<<(2 * 512 * 128 + PBLK - 1) / PBLK, PBLK, 0, stream>>>(pw1, packP, 2, ipp);
    pack_w1<512><<<(3 * 512 * 128 + PBLK - 1) / PBLK, PBLK, 0, stream>>>(iw1, packI, 3, ipi);

    // ---- term kernels ----
    term_mfma<1, 1, 2><<<(N  + 63) / 64, 256, 0, stream>>>(nodeb, nullptr, packA, ab1, aw2, ab2, out_a, N);
    term_mfma<2, 2, 2><<<(NB + 63) / 64, 256, 0, stream>>>(nodeb, bidx,    packB, bb1, bw2, bb2, out_b, NB);
    term_mfma<3, 2, 2><<<(NA + 63) / 64, 256, 0, stream>>>(nodeb, gidx,    packG, gb1, gw2, gb2, out_g, NA);
    term_mfma<4, 2, 6><<<(NP + 63) / 64, 256, 0, stream>>>(nodeb, pidx,    packP, pb1, pw2, pb2, out_p, NP);
    term_mfma<4, 3, 6><<<(NI + 63) / 64, 256, 0, stream>>>(nodeb, iidx,    packI, ib1, iw2, ib2, out_i, NI);
}

// Round 7
// 413.396 us; speedup vs baseline: 1.0608x; 1.0608x over previous
//
#include <hip/hip_runtime.h>

#define PBLK 256

typedef __attribute__((ext_vector_type(8))) short bf16x8;
typedef __attribute__((ext_vector_type(16))) float f32x16;

__device__ __forceinline__ unsigned short f2bf(float x) {
    unsigned int u = __builtin_bit_cast(unsigned int, x);
    u += 0x7fffu + ((u >> 16) & 1u);
    return (unsigned short)(u >> 16);
}

// ---- pre-pass 1: node_reps fp32 -> bf16 ----
__global__ void conv_node(const float* __restrict__ x, unsigned short* __restrict__ o, int n4) {
    int tid = blockIdx.x * PBLK + threadIdx.x;
    if (tid >= n4) return;
    const float4 v = reinterpret_cast<const float4*>(x)[tid];
    ushort4 r;
    r.x = f2bf(v.x); r.y = f2bf(v.y); r.z = f2bf(v.z); r.w = f2bf(v.w);
    reinterpret_cast<ushort4*>(o)[tid] = r;
}

// ---- pre-pass 2: pack w1 (K x 128) into SINGLE-copy 32x32x16 B-frag layout ----
// o[((ct*KS + s)*64 + l)*8 + j]; lane l -> col = ct*32+(l&31), k = s*16+(l>>5)*8+j.
// No perm duplication: weight blocks are shared across perms (slot changes, not W).
template<int K>
__global__ void pack_w1(const float* __restrict__ w1, unsigned short* __restrict__ o) {
    constexpr int KS = K / 16;
    int tid = blockIdx.x * PBLK + threadIdx.x;
    if (tid >= K * 128) return;
    const int j = tid & 7;
    const int l = (tid >> 3) & 63;
    const int cts = tid >> 9;          // ct*KS + s
    const int s  = cts % KS;
    const int ct = cts / KS;
    const int col = ct * 32 + (l & 31);
    const int k = s * 16 + (l >> 5) * 8 + j;
    o[tid] = f2bf(w1[(size_t)k * 128 + col]);
}

// ---- async global->LDS, 16B per lane ----
__device__ __forceinline__ void gld_lds16(const unsigned short* g, unsigned char* l) {
    typedef __attribute__((address_space(1))) unsigned int GU;
    typedef __attribute__((address_space(3))) unsigned int LU;
    __builtin_amdgcn_global_load_lds((GU*)g, (LU*)l, 16, 0, 0);
}

// ---- per-term config: forward perms (weight block b multiplies x-slot P[p][b]) ----
template<int TERM> struct TC;
template<> struct TC<0> { static constexpr int NA = 1, NP = 1, DO = 2;
                          static constexpr int P[1][4] = {{0,0,0,0}}; };
template<> struct TC<1> { static constexpr int NA = 2, NP = 2, DO = 2;
                          static constexpr int P[2][4] = {{0,1,0,0},{1,0,0,0}}; };
template<> struct TC<2> { static constexpr int NA = 3, NP = 2, DO = 2;
                          static constexpr int P[2][4] = {{0,1,2,0},{2,1,0,0}}; };
template<> struct TC<3> { static constexpr int NA = 4, NP = 2, DO = 6;
                          static constexpr int P[2][4] = {{0,1,2,3},{3,2,1,0}}; };
template<> struct TC<4> { static constexpr int NA = 4, NP = 3, DO = 6;
                          static constexpr int P[3][4] = {{0,1,2,3},{2,1,3,0},{3,1,0,2}}; };

// ---- main term kernel ----
// Block = 64 rows x 128 cols, 256 threads = 4 waves; wave tile 64 rows x 32 cols
// (acc = NPERMS x 2 row-tiles of f32x16). Full X tile (all atoms) gathered to
// LDS once per block via glds burst + one __syncthreads (its implicit vmcnt(0)
// drain is the needed wait). K-loop: weight blocks SHARED across perms — each
// B-frag loaded once (register-double-buffered groups of 4) and multiplied
// against NPERMS different A-slots read from LDS.
template<int TERM>
__global__ __launch_bounds__(256, 2) void term_mfma(
    const unsigned short* __restrict__ nodeb,  // (N,128) bf16
    const int* __restrict__ idx,               // (nrows,NATOMS) or nullptr
    const unsigned short* __restrict__ pack,   // K*128 bf16 packed (single copy)
    const float* __restrict__ b1,              // (128)
    const float* __restrict__ w2,              // (128,DOUT)
    const float* __restrict__ b2,              // (DOUT)
    float* __restrict__ out,                   // (nrows,DOUT)
    int nrows)
{
    constexpr int NATOMS = TC<TERM>::NA;
    constexpr int NPERMS = TC<TERM>::NP;
    constexpr int DOUT   = TC<TERM>::DO;
    constexpr int KS     = NATOMS * 8;         // k-steps of 16
    constexpr int XB     = NATOMS * 16384;     // X bytes (64 rows x 256B per atom)
    constexpr int LB     = XB > 32768 ? XB : 32768;
    __shared__ __align__(16) unsigned char lds[LB];

    const int t   = threadIdx.x;
    const int l   = t & 63;
    const int cg  = t >> 6;                    // wave id = col-tile (32 cols)
    const int l31 = l & 31;
    const int hi  = l >> 5;
    const int r0  = blockIdx.x * 64;

    // gather indices for this wave's 16 staging rows x NATOMS
    int nr[NATOMS][4];
    #pragma unroll
    for (int a = 0; a < NATOMS; ++a)
        #pragma unroll
        for (int q = 0; q < 4; ++q) {
            const int rl = cg * 16 + q * 4 + (l >> 4);
            int gr = r0 + rl; if (gr >= nrows) gr = nrows - 1;
            nr[a][q] = idx ? idx[gr * NATOMS + a] : gr;
        }

    // glds burst: whole X tile (linear LDS dest, inverse-swizzled source)
    #pragma unroll
    for (int a = 0; a < NATOMS; ++a)
        #pragma unroll
        for (int q = 0; q < 4; ++q) {
            const int rl = cg * 16 + q * 4 + (l >> 4);
            const unsigned short* src = nodeb + (size_t)nr[a][q] * 128
                                        + (((l & 15) ^ (rl & 15)) << 3);
            gld_lds16(src, lds + a * 16384 + (cg * 16 + q * 4) * 256);
        }

    const int col = cg * 32 + l31;
    const float bv = b1[col];
    f32x16 acc[NPERMS][2];
    #pragma unroll
    for (int p = 0; p < NPERMS; ++p)
        #pragma unroll
        for (int rt = 0; rt < 2; ++rt)
            #pragma unroll
            for (int i = 0; i < 16; ++i) acc[p][rt][i] = bv;

    __syncthreads();   // implicit vmcnt(0): all waves' glds landed

    // ---- k-loop: B groups of 4, double-buffered in registers ----
    bf16x8 Bb[2][4];
#define LOADBG(buf_, gi_) { _Pragma("unroll")                                      \
    for (int s4_ = 0; s4_ < 4; ++s4_)                                              \
        buf_[s4_] = *reinterpret_cast<const bf16x8*>(                              \
            pack + (((size_t)cg * KS + (gi_) * 4 + s4_) * 64 + l) * 8); }

    LOADBG(Bb[0], 0);
    #pragma unroll
    for (int b = 0; b < NATOMS; ++b) {
        #pragma unroll
        for (int g = 0; g < 2; ++g) {
            const int gi = b * 2 + g;
            if (gi + 1 < NATOMS * 2) LOADBG(Bb[(gi + 1) & 1], gi + 1);
            #pragma unroll
            for (int s4 = 0; s4 < 4; ++s4) {
                const int kb = g * 4 + s4;     // k-step within weight block
                #pragma unroll
                for (int p = 0; p < NPERMS; ++p) {
                    const int slot = TC<TERM>::P[p][b];   // compile-time
                    #pragma unroll
                    for (int rt = 0; rt < 2; ++rt) {
                        const int row = rt * 32 + l31;
                        const bf16x8 av = *reinterpret_cast<const bf16x8*>(
                            lds + slot * 16384 + row * 256
                                + (((kb * 2 + hi) ^ (row & 15)) << 4));
                        acc[p][rt] = __builtin_amdgcn_mfma_f32_32x32x16_bf16(
                            av, Bb[gi & 1][s4], acc[p][rt], 0, 0, 0);
                    }
                }
            }
        }
    }
#undef LOADBG

    __syncthreads();   // all A-reads done before overwriting X with h

    // ---- h = sum_p relu(acc_p) -> LDS (fp32, swizzled); C layout per m74/m101 ----
    float* hs = reinterpret_cast<float*>(lds);
    #pragma unroll
    for (int rt = 0; rt < 2; ++rt)
        #pragma unroll
        for (int i = 0; i < 16; ++i) {
            const int rowl = rt * 32 + (i & 3) + 8 * (i >> 2) + 4 * hi;
            float v = 0.0f;
            #pragma unroll
            for (int p = 0; p < NPERMS; ++p) v += fmaxf(acc[p][rt][i], 0.0f);
            hs[rowl * 128 + (col ^ ((rowl & 7) << 2))] = v;
        }
    __syncthreads();

    // ---- layer 2: y = h @ w2 + NPERMS*b2 ----
    for (int q = t; q < 64 * DOUT; q += 256) {
        const int r = q / DOUT;
        const int o = q - r * DOUT;
        float y0 = 0.f, y1 = 0.f, y2 = 0.f, y3 = 0.f;
        #pragma unroll 4
        for (int c = 0; c < 128; c += 4) {
            y0 += hs[r * 128 + ((c    ) ^ ((r & 7) << 2))] * w2[(size_t)(c    ) * DOUT + o];
            y1 += hs[r * 128 + ((c + 1) ^ ((r & 7) << 2))] * w2[(size_t)(c + 1) * DOUT + o];
            y2 += hs[r * 128 + ((c + 2) ^ ((r & 7) << 2))] * w2[(size_t)(c + 2) * DOUT + o];
            y3 += hs[r * 128 + ((c + 3) ^ ((r & 7) << 2))] * w2[(size_t)(c + 3) * DOUT + o];
        }
        const float y = b2[o] * (float)NPERMS + ((y0 + y1) + (y2 + y3));
        const int row = r0 + r;
        if (row < nrows) out[(size_t)row * DOUT + o] = y;
    }
}

extern "C" void kernel_launch(void* const* d_in, const int* in_sizes, int n_in,
                              void* d_out, int out_size, void* d_ws, size_t ws_size,
                              hipStream_t stream) {
    const float* node = (const float*)d_in[0];
    const int* bidx = (const int*)d_in[1];
    const int* gidx = (const int*)d_in[2];
    const int* pidx = (const int*)d_in[3];
    const int* iidx = (const int*)d_in[4];

    const float* aw1 = (const float*)d_in[5];
    const float* ab1 = (const float*)d_in[6];
    const float* aw2 = (const float*)d_in[7];
    const float* ab2 = (const float*)d_in[8];
    const float* bw1 = (const float*)d_in[9];
    const float* bb1 = (const float*)d_in[10];
    const float* bw2 = (const float*)d_in[11];
    const float* bb2 = (const float*)d_in[12];
    const float* gw1 = (const float*)d_in[13];
    const float* gb1 = (const float*)d_in[14];
    const float* gw2 = (const float*)d_in[15];
    const float* gb2 = (const float*)d_in[16];
    const float* pw1 = (const float*)d_in[17];
    const float* pb1 = (const float*)d_in[18];
    const float* pw2 = (const float*)d_in[19];
    const float* pb2 = (const float*)d_in[20];
    const float* iw1 = (const float*)d_in[21];
    const float* ib1 = (const float*)d_in[22];
    const float* iw2 = (const float*)d_in[23];
    const float* ib2 = (const float*)d_in[24];

    const int N  = in_sizes[0] / 128;
    const int NB = in_sizes[1] / 2;
    const int NA = in_sizes[2] / 3;
    const int NP = in_sizes[3] / 4;
    const int NI = in_sizes[4] / 4;

    float* out   = (float*)d_out;
    float* out_a = out;
    float* out_b = out_a + (size_t)N  * 2;
    float* out_g = out_b + (size_t)NB * 2;
    float* out_p = out_g + (size_t)NA * 2;
    float* out_i = out_p + (size_t)NP * 6;

    // ---- workspace layout (bf16 elements) ----
    unsigned short* nodeb = (unsigned short*)d_ws;
    size_t off = (size_t)N * 128;
    unsigned short* packA = nodeb + off; off += (size_t)128 * 128;
    unsigned short* packB = nodeb + off; off += (size_t)256 * 128;
    unsigned short* packG = nodeb + off; off += (size_t)384 * 128;
    unsigned short* packP = nodeb + off; off += (size_t)512 * 128;
    unsigned short* packI = nodeb + off; off += (size_t)512 * 128;

    // ---- pre-pass: convert node, pack weights (single copies) ----
    {
        const int n4 = N * 128 / 4;
        conv_node<<<(n4 + PBLK - 1) / PBLK, PBLK, 0, stream>>>(node, nodeb, n4);
    }
    pack_w1<128><<<(128 * 128 + PBLK - 1) / PBLK, PBLK, 0, stream>>>(aw1, packA);
    pack_w1<256><<<(256 * 128 + PBLK - 1) / PBLK, PBLK, 0, stream>>>(bw1, packB);
    pack_w1<384><<<(384 * 128 + PBLK - 1) / PBLK, PBLK, 0, stream>>>(gw1, packG);
    pack_w1<512><<<(512 * 128 + PBLK - 1) / PBLK, PBLK, 0, stream>>>(pw1, packP);
    pack_w1<512><<<(512 * 128 + PBLK - 1) / PBLK, PBLK, 0, stream>>>(iw1, packI);

    // ---- term kernels ----
    term_mfma<0><<<(N  + 63) / 64, 256, 0, stream>>>(nodeb, nullptr, packA, ab1, aw2, ab2, out_a, N);
    term_mfma<1><<<(NB + 63) / 64, 256, 0, stream>>>(nodeb, bidx,    packB, bb1, bw2, bb2, out_b, NB);
    term_mfma<2><<<(NA + 63) / 64, 256, 0, stream>>>(nodeb, gidx,    packG, gb1, gw2, gb2, out_g, NA);
    term_mfma<3><<<(NP + 63) / 64, 256, 0, stream>>>(nodeb, pidx,    packP, pb1, pw2, pb2, out_p, NP);
    term_mfma<4><<<(NI + 63) / 64, 256, 0, stream>>>(nodeb, iidx,    packI, ib1, iw2, ib2, out_i, NI);
}

// Round 8
// 382.162 us; speedup vs baseline: 1.1475x; 1.0817x over previous
//
#include <hip/hip_runtime.h>

#define PBLK 256

typedef __attribute__((ext_vector_type(8))) short bf16x8;
typedef __attribute__((ext_vector_type(16))) float f32x16;

struct IPerm { int v[12]; };   // up to 3 perms x 4 atoms (inverse perms)

__device__ __forceinline__ unsigned short f2bf(float x) {
    unsigned int u = __builtin_bit_cast(unsigned int, x);
    u += 0x7fffu + ((u >> 16) & 1u);
    return (unsigned short)(u >> 16);
}

// ---- pre-pass 1: node_reps fp32 -> bf16 ----
__global__ void conv_node(const float* __restrict__ x, unsigned short* __restrict__ o, int n4) {
    int tid = blockIdx.x * PBLK + threadIdx.x;
    if (tid >= n4) return;
    const float4 v = reinterpret_cast<const float4*>(x)[tid];
    ushort4 r;
    r.x = f2bf(v.x); r.y = f2bf(v.y); r.z = f2bf(v.z); r.w = f2bf(v.w);
    reinterpret_cast<ushort4*>(o)[tid] = r;
}

// ---- pre-pass 2: pack w1 into per-perm 32x32x16 B-fragment layout ----
// o[(((p*4+ct)*KS + s)*64 + l)*8 + j]; lane l -> col = ct*32+(l&31),
// k = s*16 + (l>>5)*8 + j; source row permuted per inverse perm on 128-blocks.
// (HW-verified correct in round 5.)
template<int K>
__global__ void pack_w1(const float* __restrict__ w1, unsigned short* __restrict__ o,
                        int nperms, IPerm ip) {
    constexpr int KS = K / 16;
    const int per = K * 128;
    int tid = blockIdx.x * PBLK + threadIdx.x;
    if (tid >= nperms * per) return;
    const int p = tid / per;
    const int e = tid - p * per;
    const int j = e & 7;
    const int l = (e >> 3) & 63;
    const int cts = e >> 9;            // ct*KS + s
    const int s  = cts % KS;
    const int ct = cts / KS;
    const int col = ct * 32 + (l & 31);
    const int k = s * 16 + (l >> 5) * 8 + j;
    const int srow = ip.v[p * 4 + (k >> 7)] * 128 + (k & 127);
    o[tid] = f2bf(w1[(size_t)srow * 128 + col]);
}

// ---- async global->LDS, 16B per lane ----
__device__ __forceinline__ void gld_lds16(const unsigned short* g, unsigned char* l) {
    typedef __attribute__((address_space(1))) unsigned int GU;
    typedef __attribute__((address_space(3))) unsigned int LU;
    __builtin_amdgcn_global_load_lds((GU*)g, (LU*)l, 16, 0, 0);
}

template<int N> __device__ __forceinline__ void waitvm() {
    if constexpr (N == 0) asm volatile("s_waitcnt vmcnt(0)" ::: "memory");
    else                  asm volatile("s_waitcnt vmcnt(2)" ::: "memory");
}

// raw barrier
__device__ __forceinline__ void bar() {
    asm volatile("" ::: "memory");
    __builtin_amdgcn_s_barrier();
    asm volatile("" ::: "memory");
}

// ---- main term kernel ----
// ROWS=64 rows/block, 512 threads = 8 waves (2 row-grp x 4 col-grp), wave tile
// 32 rows x 32 cols, mfma_f32_32x32x16_bf16. X staged per-atom via
// global_load_lds (16KB double-buffer). Per atom: the NPERMS*8 B-fragments are
// issued as ONE batch, pinned by sched_barrier(0) so every load gets its own
// destination register and all are in flight concurrently (round-5's defect:
// the scheduler serialized them into 16 dependent ~500cy latencies).
template<int NATOMS, int NPERMS, int DOUT>
__global__ __launch_bounds__(512, 2) void term_mfma(
    const unsigned short* __restrict__ nodeb,  // (N,128) bf16
    const int* __restrict__ idx,               // (nrows,NATOMS) or nullptr
    const unsigned short* __restrict__ pack,   // NPERMS*K*128 bf16 packed
    const float* __restrict__ b1,              // (128)
    const float* __restrict__ w2,              // (128,DOUT)
    const float* __restrict__ b2,              // (DOUT)
    float* __restrict__ out,                   // (nrows,DOUT)
    int nrows)
{
    constexpr int ROWS = 64;
    constexpr int KS   = NATOMS * 8;           // total k-steps of 16
    constexpr int ABUF = ROWS * 256;           // 16KB per atom buffer
    __shared__ __align__(16) unsigned char lds[2 * ABUF];   // 32KB (h reuses)

    const int t    = threadIdx.x;
    const int l    = t & 63;
    const int w    = t >> 6;
    const int hi32 = l >> 5;
    const int l31  = l & 31;
    const int rg   = w >> 2;
    const int cg   = w & 3;
    const int r0   = blockIdx.x * ROWS;
    const int rb   = w * 8;

    // prefetch gather indices into registers
    int nrow_r[NATOMS * 2];
    #pragma unroll
    for (int a = 0; a < NATOMS; ++a)
        #pragma unroll
        for (int q = 0; q < 2; ++q) {
            const int rl = rb + q * 4 + (l >> 4);
            int row = r0 + rl; if (row >= nrows) row = nrows - 1;
            nrow_r[a * 2 + q] = idx ? idx[row * NATOMS + a] : row;
        }

#define STAGE(A, BSEL) do {                                                          \
    unsigned char* buf_ = lds + (BSEL) * ABUF;                                       \
    _Pragma("unroll")                                                                \
    for (int q_ = 0; q_ < 2; ++q_) {                                                 \
        const int rl_ = rb + q_ * 4 + (l >> 4);                                      \
        const unsigned short* src_ = nodeb + (size_t)nrow_r[(A) * 2 + q_] * 128      \
                                     + (((l & 15) ^ (rl_ & 15)) << 3);               \
        gld_lds16(src_, buf_ + (rb + q_ * 4) * 256);                                 \
    } } while (0)

    const int col = cg * 32 + l31;
    const float bv = b1[col];
    f32x16 acc[NPERMS];
    #pragma unroll
    for (int p = 0; p < NPERMS; ++p)
        #pragma unroll
        for (int i = 0; i < 16; ++i) acc[p][i] = bv;

    STAGE(0, 0);
    if (NATOMS > 1) STAGE(1, 1);

    #pragma unroll
    for (int a = 0; a < NATOMS; ++a) {
        // glds for this atom are the oldest outstanding VMEM ops; the 2 newest
        // (if any) are next-next atom's glds -> waitvm<2> mid-loop, <0> at end.
        if (a + 1 < NATOMS) waitvm<2>(); else waitvm<0>();
        bar();

        // ---- batched B-fragment loads: ALL issued before ANY use ----
        bf16x8 B[NPERMS * 8];
        #pragma unroll
        for (int p = 0; p < NPERMS; ++p)
            #pragma unroll
            for (int s = 0; s < 8; ++s)
                B[p * 8 + s] = *reinterpret_cast<const bf16x8*>(
                    pack + (((size_t)(p * 4 + cg) * KS + (a * 8 + s)) * 64 + l) * 8);
        __builtin_amdgcn_sched_barrier(0);   // pin: loads above, compute below

        const unsigned char* xb = lds + (a & 1) * ABUF;
        const int rowb = rg * 32 + l31;
        #pragma unroll
        for (int s = 0; s < 8; ++s) {
            const bf16x8 av = *reinterpret_cast<const bf16x8*>(
                xb + rowb * 256 + (((s * 2 + hi32) ^ (l & 15)) << 4));
            #pragma unroll
            for (int p = 0; p < NPERMS; ++p)
                acc[p] = __builtin_amdgcn_mfma_f32_32x32x16_bf16(av, B[p * 8 + s], acc[p], 0, 0, 0);
        }
        asm volatile("s_waitcnt lgkmcnt(0)" ::: "memory");   // ds_reads retired
        bar();
        if (a + 2 < NATOMS) STAGE(a + 2, a & 1);             // refill freed buffer
    }
#undef STAGE

    // ---- h = sum_p relu(acc_p) -> LDS (fp32, swizzled); C layout per m74/m101 ----
    float* hs = reinterpret_cast<float*>(lds);
    #pragma unroll
    for (int i = 0; i < 16; ++i) {
        const int rowl = rg * 32 + (i & 3) + 8 * (i >> 2) + 4 * hi32;
        float v = 0.0f;
        #pragma unroll
        for (int p = 0; p < NPERMS; ++p) v += fmaxf(acc[p][i], 0.0f);
        hs[rowl * 128 + (col ^ ((rowl & 7) << 2))] = v;
    }
    __syncthreads();

    // ---- layer 2: y = h @ w2 + NPERMS*b2 ----
    if (t < ROWS * DOUT) {
        const int r = t / DOUT;
        const int o = t - r * DOUT;
        float y0 = 0.f, y1 = 0.f, y2 = 0.f, y3 = 0.f;
        #pragma unroll 4
        for (int c = 0; c < 128; c += 4) {
            y0 += hs[r * 128 + ((c    ) ^ ((r & 7) << 2))] * w2[(size_t)(c    ) * DOUT + o];
            y1 += hs[r * 128 + ((c + 1) ^ ((r & 7) << 2))] * w2[(size_t)(c + 1) * DOUT + o];
            y2 += hs[r * 128 + ((c + 2) ^ ((r & 7) << 2))] * w2[(size_t)(c + 2) * DOUT + o];
            y3 += hs[r * 128 + ((c + 3) ^ ((r & 7) << 2))] * w2[(size_t)(c + 3) * DOUT + o];
        }
        const float y = b2[o] * (float)NPERMS + ((y0 + y1) + (y2 + y3));
        const int row = r0 + r;
        if (row < nrows) out[(size_t)row * DOUT + o] = y;
    }
}

extern "C" void kernel_launch(void* const* d_in, const int* in_sizes, int n_in,
                              void* d_out, int out_size, void* d_ws, size_t ws_size,
                              hipStream_t stream) {
    const float* node = (const float*)d_in[0];
    const int* bidx = (const int*)d_in[1];
    const int* gidx = (const int*)d_in[2];
    const int* pidx = (const int*)d_in[3];
    const int* iidx = (const int*)d_in[4];

    const float* aw1 = (const float*)d_in[5];
    const float* ab1 = (const float*)d_in[6];
    const float* aw2 = (const float*)d_in[7];
    const float* ab2 = (const float*)d_in[8];
    const float* bw1 = (const float*)d_in[9];
    const float* bb1 = (const float*)d_in[10];
    const float* bw2 = (const float*)d_in[11];
    const float* bb2 = (const float*)d_in[12];
    const float* gw1 = (const float*)d_in[13];
    const float* gb1 = (const float*)d_in[14];
    const float* gw2 = (const float*)d_in[15];
    const float* gb2 = (const float*)d_in[16];
    const float* pw1 = (const float*)d_in[17];
    const float* pb1 = (const float*)d_in[18];
    const float* pw2 = (const float*)d_in[19];
    const float* pb2 = (const float*)d_in[20];
    const float* iw1 = (const float*)d_in[21];
    const float* ib1 = (const float*)d_in[22];
    const float* iw2 = (const float*)d_in[23];
    const float* ib2 = (const float*)d_in[24];

    const int N  = in_sizes[0] / 128;
    const int NB = in_sizes[1] / 2;
    const int NA = in_sizes[2] / 3;
    const int NP = in_sizes[3] / 4;
    const int NI = in_sizes[4] / 4;

    float* out   = (float*)d_out;
    float* out_a = out;
    float* out_b = out_a + (size_t)N  * 2;
    float* out_g = out_b + (size_t)NB * 2;
    float* out_p = out_g + (size_t)NA * 2;
    float* out_i = out_p + (size_t)NP * 6;

    // ---- workspace layout (bf16 elements) ----
    unsigned short* nodeb = (unsigned short*)d_ws;
    size_t off = (size_t)N * 128;
    unsigned short* packA = nodeb + off; off += (size_t)1 * 128 * 128;
    unsigned short* packB = nodeb + off; off += (size_t)2 * 256 * 128;
    unsigned short* packG = nodeb + off; off += (size_t)2 * 384 * 128;
    unsigned short* packP = nodeb + off; off += (size_t)2 * 512 * 128;
    unsigned short* packI = nodeb + off; off += (size_t)3 * 512 * 128;

    // ---- pre-pass: convert node, pack weights ----
    {
        const int n4 = N * 128 / 4;
        conv_node<<<(n4 + PBLK - 1) / PBLK, PBLK, 0, stream>>>(node, nodeb, n4);
    }
    IPerm ipa{{0,0,0,0,  0,0,0,0,  0,0,0,0}};
    IPerm ipb{{0,1,0,0,  1,0,0,0,  0,0,0,0}};
    IPerm ipg{{0,1,2,0,  2,1,0,0,  0,0,0,0}};
    IPerm ipp{{0,1,2,3,  3,2,1,0,  0,0,0,0}};
    IPerm ipi{{0,1,2,3,  3,1,0,2,  2,1,3,0}};   // inverses of (0123),(2130),(3102)

    pack_w1<128><<<(1 * 128 * 128 + PBLK - 1) / PBLK, PBLK, 0, stream>>>(aw1, packA, 1, ipa);
    pack_w1<256><<<(2 * 256 * 128 + PBLK - 1) / PBLK, PBLK, 0, stream>>>(bw1, packB, 2, ipb);
    pack_w1<384><<<(2 * 384 * 128 + PBLK - 1) / PBLK, PBLK, 0, stream>>>(gw1, packG, 2, ipg);
    pack_w1<512><<<(2 * 512 * 128 + PBLK - 1) / PBLK, PBLK, 0, stream>>>(pw1, packP, 2, ipp);
    pack_w1<512><<<(3 * 512 * 128 + PBLK - 1) / PBLK, PBLK, 0, stream>>>(iw1, packI, 3, ipi);

    // ---- term kernels ----
    term_mfma<1, 1, 2><<<(N  + 63) / 64, 512, 0, stream>>>(nodeb, nullptr, packA, ab1, aw2, ab2, out_a, N);
    term_mfma<2, 2, 2><<<(NB + 63) / 64, 512, 0, stream>>>(nodeb, bidx,    packB, bb1, bw2, bb2, out_b, NB);
    term_mfma<3, 2, 2><<<(NA + 63) / 64, 512, 0, stream>>>(nodeb, gidx,    packG, gb1, gw2, gb2, out_g, NA);
    term_mfma<4, 2, 6><<<(NP + 63) / 64, 512, 0, stream>>>(nodeb, pidx,    packP, pb1, pw2, pb2, out_p, NP);
    term_mfma<4, 3, 6><<<(NI + 63) / 64, 512, 0, stream>>>(nodeb, iidx,    packI, ib1, iw2, ib2, out_i, NI);
}